// Round 7
// baseline (128.940 us; speedup 1.0000x reference)
//
#include <hip/hip_runtime.h>
#include <cmath>

static constexpr int kC = 1024;
static constexpr int kD = 768;
static constexpr int kThreads = 256;      // prep block
static constexpr int kThreadsF = 1024;    // fused block (16 waves)
static constexpr float kTauInv = 10.0f;
static constexpr int kKS = kD / 32;       // 24 K-steps
static constexpr int kMaxPos = 128;       // per-batch anchor capacity (actual ~51)
static constexpr int kMT = kMaxPos / 16;  // 8 M-tiles per batch
static constexpr int kSS = 193;           // float4 stage stride per row
static constexpr int kSimsStride = 1028;  // floats; %32==4

typedef __attribute__((ext_vector_type(8))) short short8_t;
typedef __attribute__((ext_vector_type(4))) float f32x4_t;
union I4S8 { int4 i; short8_t s; };

__device__ __forceinline__ unsigned fkey(float f) {
  unsigned b = __float_as_uint(f);
  return (b & 0x80000000u) ? ~b : (b | 0x80000000u);
}

// round-to-nearest-even fp32 -> bf16 bits
__device__ __forceinline__ unsigned bfr(float x) {
  unsigned u = __float_as_uint(x);
  return (u + 0x7fffu + ((u >> 16) & 1u)) >> 16;
}

// wave-uniform count of a 16-element-per-lane predicate set via ballot+popcount
#define BALLOT_COUNT16(expr, dst)                       \
  {                                                     \
    int c__ = 0;                                        \
    _Pragma("unroll")                                   \
    for (int j = 0; j < 16; ++j)                        \
      c__ += (int)__popcll(__ballot(expr));             \
    dst = c__;                                          \
  }

// ---- K1 (fused prep): blocks 0..63 pack prototypes; blocks 64..79 rand-select per batch ----
__global__ void __launch_bounds__(kThreads) prep_kernel(
    const float* __restrict__ p, const int* __restrict__ targets,
    const float* __restrict__ rs, int4* __restrict__ pnf,
    int* __restrict__ flags, int* __restrict__ cnt, float* __restrict__ poscnt,
    int* __restrict__ alist, float* __restrict__ out, int K_rand) {
  __shared__ float4 pstage[16 * kSS];
  __shared__ float scl[16];
  __shared__ unsigned keys[kC];
  int t = threadIdx.x;
  if (blockIdx.x == 0 && t == 0) *out = 0.f;

  if (blockIdx.x < 64) {
    int n0 = blockIdx.x * 16;
    const float4* psrc = (const float4*)p + (size_t)n0 * (kD / 4);
    #pragma unroll
    for (int i = 0; i < 12; ++i) {
      int j = t + 256 * i;
      int r = j / 192, o = j % 192;
      pstage[r * kSS + o] = psrc[j];
    }
    __syncthreads();
    {
      int r = t >> 4, part = t & 15;
      float ss = 0.f;
      #pragma unroll
      for (int i = 0; i < 12; ++i) {
        float4 v = pstage[r * kSS + part * 12 + i];
        ss += v.x * v.x + v.y * v.y + v.z * v.z + v.w * v.w;
      }
      #pragma unroll
      for (int off = 8; off > 0; off >>= 1) ss += __shfl_xor(ss, off, 16);
      if (part == 0) scl[r] = 1.0f / fmaxf(sqrtf(ss), 1e-12f);
    }
    __syncthreads();
    const float* pst = (const float*)pstage;
    #pragma unroll
    for (int i = 0; i < 6; ++i) {
      int chunk = i * 256 + t;
      int ks = chunk >> 6;
      int ln = chunk & 63;
      int col = ln & 15;
      int k0 = ks * 32 + (ln >> 4) * 8;
      const float* src = pst + col * (kSS * 4) + k0;
      float s = scl[col];
      float4 a = *(const float4*)(src);
      float4 b = *(const float4*)(src + 4);
      int4 pk;
      pk.x = bfr(a.x * s) | (bfr(a.y * s) << 16);
      pk.y = bfr(a.z * s) | (bfr(a.w * s) << 16);
      pk.z = bfr(b.x * s) | (bfr(b.y * s) << 16);
      pk.w = bfr(b.z * s) | (bfr(b.w * s) << 16);
      pnf[(size_t)((blockIdx.x * kKS + ks) << 6) + ln] = pk;
    }
  } else {
    int b = blockIdx.x - 64;
    int wq = t >> 6, ln = t & 63;
    #pragma unroll
    for (int k = 0; k < 4; ++k) {
      int e = t + 256 * k;
      int tg = targets[b * kC + e];
      float v = (tg == 0) ? rs[b * kC + e] : -INFINITY;
      keys[e] = fkey(v);  // positives -> fkey(-inf) < 0x80000000 <= fkey(rs>=0)
    }
    __syncthreads();
    unsigned mk[16];
    #pragma unroll
    for (int j = 0; j < 16; ++j) mk[j] = keys[ln + 64 * j];

    unsigned lo = 0u, hi = 0xFFFFFFFFu;
    while (lo < hi) {
      unsigned mid = lo + ((hi - lo) >> 1);
      int c_;
      BALLOT_COUNT16(mk[j] > mid, c_);
      if (c_ >= K_rand) lo = mid + 1u; else hi = mid;
    }
    unsigned thr = lo;

    int n_g, n_eq, cp;
    BALLOT_COUNT16(mk[j] > thr, n_g);
    BALLOT_COUNT16(mk[j] == thr, n_eq);
    BALLOT_COUNT16(mk[j] < 0x80000000u, cp);
    int need = K_rand - n_g;
    bool take_all_eq = (n_eq <= need);

    if (t == 0) {
      poscnt[b] = fmaxf((float)cp, 1.f);
      cnt[b] = (cp < kMaxPos) ? cp : kMaxPos;
    }

    if (wq == 0) {
      int pref = 0;
      #pragma unroll
      for (int j = 0; j < 16; ++j) {
        unsigned long long ball = __ballot(mk[j] < 0x80000000u);
        if (mk[j] < 0x80000000u) {
          int rank = pref + __popcll(ball & ((1ull << ln) - 1ull));
          if (rank < kMaxPos) alist[b * kMaxPos + rank] = ln + 64 * j;
        }
        pref += __popcll(ball);
      }
    }

    if (take_all_eq) {
      #pragma unroll
      for (int k = 0; k < 4; ++k) {
        int j = wq + 4 * k;
        int e = ln + 64 * j;  // == t + 256*k
        unsigned kk = mk[j];
        int sel = (kk >= thr && kk >= 0x80000000u) ? 1 : 0;
        int pos = (kk < 0x80000000u) ? 2 : 0;
        flags[b * kC + e] = sel | pos;
      }
    } else {
      int pref = 0;
      int rankj[16];
      #pragma unroll
      for (int j = 0; j < 16; ++j) {
        unsigned long long ball = __ballot(mk[j] == thr);
        rankj[j] = pref + __popcll(ball & ((1ull << ln) - 1ull));
        pref += __popcll(ball);
      }
      #pragma unroll
      for (int k = 0; k < 4; ++k) {
        int j = wq + 4 * k;
        int e = ln + 64 * j;
        unsigned kk = mk[j];
        int sel = (kk > thr) ? 1 : ((kk == thr && rankj[j] < need) ? 1 : 0);
        int pos = (kk < 0x80000000u) ? 2 : 0;
        flags[b * kC + e] = sel | pos;
      }
    }
  }
}

// ---- K2: fused GEMM + epilogue. grid = 16 b x 8 mt; 1024 threads = 16 waves ----
// Each wave: 4 N-tiles of the GEMM (depth-3 register prefetch), then 1 anchor row epilogue.
__global__ void __launch_bounds__(kThreadsF) fused_kernel(
    const float* __restrict__ f, const int4* __restrict__ pnf,
    const int* __restrict__ flags, const int* __restrict__ alist,
    const int* __restrict__ cnt, const float* __restrict__ poscnt,
    float* __restrict__ out, int B, int K_hard) {
  __shared__ __align__(16) char smem[kSimsStride * 16 * 4];  // 65792 B: fstage, then sims alias
  __shared__ __align__(16) int4 afrag[kKS * 64];             // 24576 B
  __shared__ int rowc[16];
  __shared__ float rowscl[16];

  int b = blockIdx.x >> 3;
  int mt = blockIdx.x & 7;
  int cb = cnt[b];
  if (mt * 16 >= cb) return;  // block-uniform
  int t = threadIdx.x;
  int wq = t >> 6, ln = t & 63;

  if (t < 16) {
    int idx = mt * 16 + t;
    rowc[t] = alist[b * kMaxPos + ((idx < cb) ? idx : (cb - 1))];
  }
  __syncthreads();

  // ---- stage 16 f rows into LDS (3072 float4, 3 per thread, coalesced) ----
  float4* fstage = (float4*)smem;
  #pragma unroll
  for (int i = 0; i < 3; ++i) {
    int j = t + kThreadsF * i;
    int r = j / 192, o = j % 192;
    fstage[r * kSS + o] = ((const float4*)f)[(size_t)(b * kC + rowc[r]) * (kD / 4) + o];
  }
  __syncthreads();

  // ---- row norms (threads 0..255) ----
  if (t < 256) {
    int r = t >> 4, part = t & 15;
    float ss = 0.f;
    #pragma unroll
    for (int i = 0; i < 12; ++i) {
      float4 v = fstage[r * kSS + part * 12 + i];
      ss += v.x * v.x + v.y * v.y + v.z * v.z + v.w * v.w;
    }
    #pragma unroll
    for (int off = 8; off > 0; off >>= 1) ss += __shfl_xor(ss, off, 16);
    if (part == 0) rowscl[r] = 1.0f / fmaxf(sqrtf(ss), 1e-12f);
  }
  __syncthreads();

  // ---- pack bf16 A-fragments (1536 chunks, <=2 per thread) ----
  {
    const float* fst = (const float*)fstage;
    #pragma unroll
    for (int i = 0; i < 2; ++i) {
      int chunk = t + kThreadsF * i;
      if (chunk < kKS * 64) {
        int ks = chunk >> 6;
        int cl = chunk & 63;
        int rr = cl & 15;
        int k0 = ks * 32 + (cl >> 4) * 8;
        const float* src = fst + rr * (kSS * 4) + k0;
        float s = rowscl[rr];
        float4 a = *(const float4*)(src);
        float4 b_ = *(const float4*)(src + 4);
        int4 pk;
        pk.x = bfr(a.x * s) | (bfr(a.y * s) << 16);
        pk.y = bfr(a.z * s) | (bfr(a.w * s) << 16);
        pk.z = bfr(b_.x * s) | (bfr(b_.y * s) << 16);
        pk.w = bfr(b_.z * s) | (bfr(b_.w * s) << 16);
        afrag[chunk] = pk;
      }
    }
  }
  __syncthreads();

  // ---- K-loop: wave wq owns N-tiles [wq*4, wq*4+4) = cols [wq*64, wq*64+64) ----
  f32x4_t acc[4];
  #pragma unroll
  for (int nt = 0; nt < 4; ++nt) acc[nt] = (f32x4_t){0.f, 0.f, 0.f, 0.f};

  {
    int gnt0 = wq * 4;
    I4S8 a[3];
    I4S8 bb[3][4];
    size_t bofs[4];
    #pragma unroll
    for (int nt = 0; nt < 4; ++nt) bofs[nt] = ((size_t)(gnt0 + nt) * kKS) * 64 + ln;

    auto LOADK = [&](int ks, int s) {
      a[s].i = afrag[ks * 64 + ln];
      #pragma unroll
      for (int nt = 0; nt < 4; ++nt) bb[s][nt].i = pnf[bofs[nt] + (size_t)ks * 64];
    };
    LOADK(0, 0);
    LOADK(1, 1);
    #pragma unroll
    for (int ks = 0; ks < kKS; ++ks) {
      int s = ks % 3;
      int sn = (ks + 2) % 3;
      if (ks + 2 < kKS) LOADK(ks + 2, sn);
      #pragma unroll
      for (int nt = 0; nt < 4; ++nt)
        acc[nt] = __builtin_amdgcn_mfma_f32_16x16x32_bf16(a[s].s, bb[s][nt].s, acc[nt], 0, 0, 0);
    }
  }

  // ---- write tempered sims to LDS (C/D layout: col=ln&15, row=(ln>>4)*4+reg) ----
  float* sims = (float*)smem;  // aliases fstage (dead)
  #pragma unroll
  for (int nt = 0; nt < 4; ++nt) {
    int col = wq * 64 + nt * 16 + (ln & 15);
    #pragma unroll
    for (int reg = 0; reg < 4; ++reg) {
      int rr = (ln >> 4) * 4 + reg;
      sims[rr * kSimsStride + col] = acc[nt][reg] * kTauInv;
    }
  }
  __syncthreads();

  // ---- epilogue: wave wq handles anchor row wq ----
  int ridx = mt * 16 + wq;
  if (ridx < cb) {
    int c = rowc[wq];
    const float* srow = sims + wq * kSimsStride;
    const int* frow = flags + b * kC;

    int fl[16];
    #pragma unroll
    for (int j = 0; j < 16; ++j) fl[j] = frow[ln + 64 * j];

    float pos = srow[c];
    float v[16]; unsigned mk[16];
    float mx = -INFINITY;
    #pragma unroll
    for (int j = 0; j < 16; ++j) {
      float s = srow[ln + 64 * j];
      float m_ = (fl[j] & 2) ? -INFINITY : s;
      v[j] = m_; mk[j] = fkey(m_);
      mx = fmaxf(mx, m_);
    }
    #pragma unroll
    for (int off = 32; off > 0; off >>= 1) mx = fmaxf(mx, __shfl_xor(mx, off, 64));

    unsigned lo = 0u, hi = 0xFFFFFFFFu;
    while (lo < hi) {
      unsigned mid = lo + ((hi - lo) >> 1);
      int c_;
      BALLOT_COUNT16(mk[j] > mid, c_);
      if (c_ >= K_hard) lo = mid + 1u; else hi = mid;
    }
    unsigned thr = lo;

    int n_g, n_eq;
    BALLOT_COUNT16(mk[j] > thr, n_g);
    BALLOT_COUNT16(mk[j] == thr, n_eq);
    int need = K_hard - n_g;

    float ssum = 0.f;
    if (n_eq <= need) {
      #pragma unroll
      for (int j = 0; j < 16; ++j) {
        float ev = (v[j] == -INFINITY) ? 0.f : __expf(v[j] - mx);
        if (mk[j] >= thr) ssum += ev;
        if (fl[j] & 1) ssum += ev;
      }
    } else {
      int pref = 0;
      #pragma unroll
      for (int j = 0; j < 16; ++j) {
        unsigned long long ball = __ballot(mk[j] == thr);
        int rank = pref + __popcll(ball & ((1ull << ln) - 1ull));
        bool selh = (mk[j] > thr) || (mk[j] == thr && rank < need);
        float ev = (v[j] == -INFINITY) ? 0.f : __expf(v[j] - mx);
        if (selh) ssum += ev;
        if (fl[j] & 1) ssum += ev;
        pref += __popcll(ball);
      }
    }
    #pragma unroll
    for (int off = 32; off > 0; off >>= 1) ssum += __shfl_xor(ssum, off, 64);

    if (ln == 0) {
      float lse = mx + logf(ssum);
      float x = lse - pos;
      float pa = (x > 0.f) ? x + log1pf(__expf(-x)) : log1pf(__expf(x));
      atomicAdd(out, pa / (poscnt[b] * (float)B));
    }
  }
}

extern "C" void kernel_launch(void* const* d_in, const int* in_sizes, int n_in,
                              void* d_out, int out_size, void* d_ws, size_t ws_size,
                              hipStream_t stream) {
  const float* f = (const float*)d_in[0];
  const float* proto = (const float*)d_in[1];
  const int* targets = (const int*)d_in[2];
  const float* rs = (const float*)d_in[3];

  const int D = in_sizes[0] / in_sizes[2];   // 768
  const int C = in_sizes[1] / D;             // 1024
  const int B = in_sizes[2] / C;             // 16
  const int K = C - 1;
  const int K_hard = (int)(K * 0.3);         // 306
  const int K_rand = K - K_hard;             // 717

  // ws layout
  char* ws = (char*)d_ws;
  int* cnt = (int*)ws;                         // 16 ints       @ 0
  float* poscnt = (float*)(ws + 256);          // 16 floats     @ 256
  int* alist = (int*)(ws + 512);               // 16*128 ints   @ 512 (8 KB)
  int* flags = (int*)(ws + 16384);             // B*C ints      @ 16 KB (64 KB)
  int4* pnf = (int4*)(ws + 131072);            // C*D bf16      @ 128 KB (1.5 MB)

  float* out = (float*)d_out;

  prep_kernel<<<80, kThreads, 0, stream>>>(proto, targets, rs, pnf, flags, cnt, poscnt, alist, out, K_rand);
  fused_kernel<<<16 * kMT, kThreadsF, 0, stream>>>(f, pnf, flags, alist, cnt, poscnt, out, B, K_hard);
}